// Round 10
// baseline (164.426 us; speedup 1.0000x reference)
//
#include <hip/hip_runtime.h>

#define NGRAPH 4096
#define NNODE  64
#define NDIM   128
#define NLAYER 3
#define PH 136   // sh pitch (bf16): 68 dwords === 4 mod 32 -> bank-uniform b128 row reads
#define PA 72    // staged-adj pitch inside sh1: 36 dwords === 4 mod 32

typedef __attribute__((ext_vector_type(8))) short short8;
typedef __attribute__((ext_vector_type(4))) float f32x4;
typedef __bf16 bf16x2 __attribute__((ext_vector_type(2)));

union S8 { short8 s8; unsigned d[4]; };

static __device__ inline ushort f2bf(float f) {  // RNE fp32 -> bf16 (fallback path)
  unsigned u = __float_as_uint(f);
  u += 0x7FFF + ((u >> 16) & 1);
  return (ushort)(u >> 16);
}

// packed fp32x2 -> bf16x2 in one HW instr on gfx950 (v_cvt_pk_bf16_f32)
static __device__ inline unsigned pkbf(float x, float y) {
#if __has_builtin(__builtin_amdgcn_cvt_pk_bf16_f32)
  bf16x2 v = __builtin_amdgcn_cvt_pk_bf16_f32(x, y);
  return __builtin_bit_cast(unsigned, v);
#else
  return (unsigned)f2bf(x) | ((unsigned)f2bf(y) << 16);
#endif
}

// W in bf16, native [l][k_out][d] layout (B-frag reads W rows directly).
__device__ __align__(16) ushort g_wbf[NLAYER * NDIM * NDIM];

__global__ __launch_bounds__(256) void convert_w(const float* __restrict__ W) {
  int i = blockIdx.x * 256 + threadIdx.x;   // 192 blocks, exact
  g_wbf[i] = f2bf(W[i]);
}

__global__ __launch_bounds__(512, 6) void mpnn_mfma(
    const int* __restrict__ fps, const float* __restrict__ adj,
    const float* __restrict__ emb, const float* __restrict__ bias,
    float* __restrict__ out) {
  __shared__ __align__(16) ushort sh0[NNODE * PH];    // h ping  17408 B
  __shared__ __align__(16) ushort sh1[NNODE * PH];    // h pong  17408 B; head doubles as adj staging

  const int g    = blockIdx.x;
  const int t    = threadIdx.x;
  const int w    = t >> 6;        // wave 0..7
  const int lane = t & 63;
  const int r    = lane & 15;     // MFMA row/col index
  const int q    = lane >> 4;     // quad 0..3
  const int n0   = w << 4;        // wave's 16-wide k_out slab (m1) == d slab (m2)

  // bpermute addresses for the z C-frag -> A-frag quad permute (R8-verified mapping)
  const int addr0 = (r + 32 * (q & 1)) << 2;   // p = 0,1
  const int addr1 = addr0 + 64;                // p = 2,3
  const bool hiQ  = (q >= 2);                  // source register select (node>=16 within 32)

  // ---- gather h0 = bf16(emb[fps]) into sh0 ----
  const int* fg = fps + g * NNODE;
#pragma unroll
  for (int it = 0; it < 4; ++it) {
    int idx = it * 512 + t;               // 2048 float4s
    int n = idx >> 5;
    int c = (idx & 31) << 2;
    float4 v = *(const float4*)(emb + fg[n] * NDIM + c);
    uint2 u = {pkbf(v.x, v.y), pkbf(v.z, v.w)};
    *(uint2*)(sh0 + n * PH + c) = u;
  }

  // ---- adjacency -> LDS (aliased into sh1's head): bf16(I + A), staged once ----
  const float* adjg = adj + (size_t)g * NNODE * NNODE;
#pragma unroll
  for (int it = 0; it < 2; ++it) {
    int idx = it * 512 + t;               // 1024 float4s
    int n = idx >> 4;
    int c = (idx & 15) << 2;
    float4 v = *(const float4*)(adjg + n * NNODE + c);
    v.x += (n == c + 0) ? 1.0f : 0.0f;    // fold residual: I + A
    v.y += (n == c + 1) ? 1.0f : 0.0f;
    v.z += (n == c + 2) ? 1.0f : 0.0f;
    v.w += (n == c + 3) ? 1.0f : 0.0f;
    uint2 u = {pkbf(v.x, v.y), pkbf(v.z, v.w)};
    *(uint2*)(sh1 + n * PA + c) = u;
  }

  // ---- bias for all layers -> registers ----
  float bv[NLAYER];
#pragma unroll
  for (int l = 0; l < NLAYER; ++l) bv[l] = bias[l * NDIM + n0 + r];

  __syncthreads();

  // ---- adjacency B-frags -> registers, ONCE (kills the per-layer 8-read redundancy) ----
  short8 fadj[4][2];
#pragma unroll
  for (int nt = 0; nt < 4; ++nt)
#pragma unroll
    for (int kh = 0; kh < 2; ++kh)
      fadj[nt][kh] = *(const short8*)(sh1 + (nt * 16 + r) * PA + kh * 32 + 8 * q);

  __syncthreads();   // staged adj fully consumed; sh1 is now free for layer-0 h-out

#pragma unroll 1   // real loop: avoid cross-layer load hoisting -> spill (R6 lesson)
  for (int l = 0; l < NLAYER; ++l) {
    const ushort* shr = (l & 1) ? sh1 : sh0;   // read buffer
    ushort*       shw = (l & 1) ? sh0 : sh1;   // write buffer (ping-pong)
    const ushort* Wl  = g_wbf + l * NDIM * NDIM;

    // ---- m1: z[node][n0-slab(16)] = relu(h * W^T + b) ----
    f32x4 acc[4];
#pragma unroll
    for (int mt = 0; mt < 4; ++mt) acc[mt] = (f32x4){bv[l], bv[l], bv[l], bv[l]};
#pragma unroll
    for (int k0 = 0; k0 < NDIM; k0 += 32) {
      short8 bw = *(const short8*)(Wl + (n0 + r) * NDIM + k0 + 8 * q);
#pragma unroll
      for (int mt = 0; mt < 4; ++mt) {
        short8 ah = *(const short8*)(shr + (mt * 16 + r) * PH + k0 + 8 * q);
        acc[mt] = __builtin_amdgcn_mfma_f32_16x16x32_bf16(ah, bw, acc[mt], 0, 0, 0);
      }
    }
    // ---- relu -> packed bf16 in registers ----
    unsigned zc[4][2];   // [mt: node tile][node pair within quad-rows]
#pragma unroll
    for (int mt = 0; mt < 4; ++mt) {
      f32x4 a = acc[mt];
      zc[mt][0] = pkbf(fmaxf(a[0], 0.f), fmaxf(a[1], 0.f));
      zc[mt][1] = pkbf(fmaxf(a[2], 0.f), fmaxf(a[3], 0.f));
    }

    // ---- m2: houtT[d in n0-slab][node'] = zT * (I+A)^T  (B = register fadj) ----
    f32x4 acc2[4];
#pragma unroll
    for (int nt = 0; nt < 4; ++nt) acc2[nt] = (f32x4){0.f, 0.f, 0.f, 0.f};
#pragma unroll
    for (int kh = 0; kh < 2; ++kh) {
      S8 az;
#pragma unroll
      for (int p = 0; p < 4; ++p) {
        int comp = p & 1;
        int lo = __builtin_amdgcn_ds_bpermute((p < 2) ? addr0 : addr1,
                                              (int)zc[2 * kh][comp]);
        int hi = __builtin_amdgcn_ds_bpermute((p < 2) ? addr0 : addr1,
                                              (int)zc[2 * kh + 1][comp]);
        az.d[p] = (unsigned)(hiQ ? hi : lo);
      }
#pragma unroll
      for (int nt = 0; nt < 4; ++nt)
        acc2[nt] = __builtin_amdgcn_mfma_f32_16x16x32_bf16(az.s8, fadj[nt][kh], acc2[nt], 0, 0, 0);
    }

    if (l < NLAYER - 1) {
      // write h into the OTHER buffer: no pre-barrier needed
#pragma unroll
      for (int nt = 0; nt < 4; ++nt) {
        f32x4 a = acc2[nt];
        uint2 u = {pkbf(a[0], a[1]), pkbf(a[2], a[3])};
        *(uint2*)(shw + (nt * 16 + r) * PH + n0 + 4 * q) = u;
      }
      __syncthreads();   // single barrier per layer
    } else {
      // ---- sum-pool: out[g][d] = sum_node' h[node'][d] ----
      f32x4 s;
#pragma unroll
      for (int i = 0; i < 4; ++i)
        s[i] = acc2[0][i] + acc2[1][i] + acc2[2][i] + acc2[3][i];
#pragma unroll
      for (int m = 1; m <= 8; m <<= 1) {
        s[0] += __shfl_xor(s[0], m);
        s[1] += __shfl_xor(s[1], m);
        s[2] += __shfl_xor(s[2], m);
        s[3] += __shfl_xor(s[3], m);
      }
      if (r == 0) {
        float4 o = {s[0], s[1], s[2], s[3]};
        *(float4*)(out + (size_t)g * NDIM + n0 + 4 * q) = o;
      }
    }
  }
}

extern "C" void kernel_launch(void* const* d_in, const int* in_sizes, int n_in,
                              void* d_out, int out_size, void* d_ws, size_t ws_size,
                              hipStream_t stream) {
  const int*   fps  = (const int*)d_in[0];
  const float* adj  = (const float*)d_in[1];
  const float* emb  = (const float*)d_in[2];
  const float* W    = (const float*)d_in[3];
  const float* bias = (const float*)d_in[4];
  float* out = (float*)d_out;

  hipLaunchKernelGGL(convert_w, dim3(192), dim3(256), 0, stream, W);
  hipLaunchKernelGGL(mpnn_mfma, dim3(NGRAPH), dim3(512), 0, stream,
                     fps, adj, emb, bias, out);
}